// Round 3
// baseline (199.705 us; speedup 1.0000x reference)
//
#include <hip/hip_runtime.h>
#include <hip/hip_bf16.h>

#define B_ 4
#define S_ 4096
#define D_ 1024
#define H_ 64
#define SCALE_ 0.125f
#define KSPLIT 4
#define SK (S_ / KSPLIT)    // 1024 K-rows per flash block

typedef __attribute__((ext_vector_type(8))) short bf16x8;
typedef __attribute__((ext_vector_type(4))) float f32x4;

// round-to-nearest-even f32 -> bf16 (finite inputs)
static __device__ __forceinline__ short f2bf(float f) {
    unsigned u = __builtin_bit_cast(unsigned, f);
    u += 0x7fffu + ((u >> 16) & 1u);
    return (short)(u >> 16);
}

// ---------------------------------------------------------------------------
// zinit: zero d_out (atomic accumulation target) + lbuf, convert wq -> bf16.
// Runs every launch (harness re-poisons out/ws each timed call).
// ---------------------------------------------------------------------------
__global__ __launch_bounds__(256) void zinit_kernel(
    const float* __restrict__ wq, short* __restrict__ wqb,
    float* __restrict__ out, float* __restrict__ lbuf)
{
    const int i = blockIdx.x * 256 + threadIdx.x;          // 0..262143
    ((f32x4*)out)[i] = (f32x4){0.f, 0.f, 0.f, 0.f};        // 1M floats
    if (i < (B_ * S_) / 4)
        ((f32x4*)lbuf)[i] = (f32x4){0.f, 0.f, 0.f, 0.f};   // 16K floats
    if (i < (H_ * D_) / 8) {
        const float* s = wq + (size_t)i * 8;
        bf16x8 v;
#pragma unroll
        for (int e = 0; e < 8; ++e) v[e] = f2bf(s[e]);
        *(bf16x8*)(wqb + (size_t)i * 8) = v;
    }
}

// ---------------------------------------------------------------------------
// qproj: q = x @ wq^T (bf16 MFMA). Block = 16 output rows x 64 cols,
// 4 waves split K=1024 into 4x256; partials combined through LDS.
// A-frags converted f32->bf16 in registers (no LDS staging); wq pre-bf16.
// ---------------------------------------------------------------------------
__global__ __launch_bounds__(256) void qproj_mfma(
    const float* __restrict__ x, const short* __restrict__ wqb,
    short* __restrict__ q)
{
    __shared__ float cs[4][16][68];   // per-wave partial C, +4 pad

    const int tid  = threadIdx.x;
    const int wave = tid >> 6;
    const int lane = tid & 63;
    const int quad = lane >> 4;
    const int lr   = lane & 15;
    const int row0 = blockIdx.x * 16;

    const float* xp = x   + (size_t)(row0 + lr) * D_ + wave * 256 + quad * 8;
    const short* wp = wqb + (size_t)lr * D_ + wave * 256 + quad * 8;

    f32x4 acc[4];
#pragma unroll
    for (int nb = 0; nb < 4; ++nb) acc[nb] = (f32x4){0.f, 0.f, 0.f, 0.f};

#pragma unroll
    for (int t = 0; t < 8; ++t) {
        const float* xpt = xp + t * 32;
        const f32x4 a0 = *(const f32x4*)xpt;
        const f32x4 a1 = *(const f32x4*)(xpt + 4);
        bf16x8 a;
#pragma unroll
        for (int e = 0; e < 4; ++e) {
            a[e]     = f2bf(a0[e]);
            a[e + 4] = f2bf(a1[e]);
        }
#pragma unroll
        for (int nb = 0; nb < 4; ++nb) {
            const bf16x8 b = *(const bf16x8*)(wp + (size_t)nb * 16 * D_ + t * 32);
            acc[nb] = __builtin_amdgcn_mfma_f32_16x16x32_bf16(a, b, acc[nb], 0, 0, 0);
        }
    }

    // stash per-wave partials (C-layout: row quad*4+i, col nb*16+lr)
#pragma unroll
    for (int nb = 0; nb < 4; ++nb)
#pragma unroll
        for (int i = 0; i < 4; ++i)
            cs[wave][quad * 4 + i][nb * 16 + lr] = acc[nb][i];
    __syncthreads();

    // combine 4 partials; each thread owns one (row, 4-col) slice
    const int r  = tid >> 4;
    const int c4 = (tid & 15) * 4;
    unsigned long long pv = 0;
#pragma unroll
    for (int j = 0; j < 4; ++j) {
        const float s = cs[0][r][c4 + j] + cs[1][r][c4 + j]
                      + cs[2][r][c4 + j] + cs[3][r][c4 + j];
        pv |= (unsigned long long)(unsigned short)f2bf(s) << (16 * j);
    }
    *(unsigned long long*)(q + (size_t)(row0 + r) * H_ + c4) = pv;
}

// ---------------------------------------------------------------------------
// flash: k = v = q, bf16 MFMA, no online max (|s*scale| <~ 15, exp safe in
// f32). Split-K across blockIdx.z: each block sums exp/PV partials over
// SK=1024 K-rows and atomically accumulates into out / lbuf.
// vt transpose writes rotated by tid&7 to kill the 8-way bank conflict.
// ---------------------------------------------------------------------------
__global__ __launch_bounds__(256) void flash_mfma(
    const short* __restrict__ q, float* __restrict__ out,
    float* __restrict__ lbuf)
{
    __shared__ short kt[64][72];       // [kcol][h]
    __shared__ short vt[64][72];       // [h][kcol]  (transposed)
    __shared__ short pl[4][16][72];    // per-wave P: [qrow][kcol]

    const int tid   = threadIdx.x;
    const int wave  = tid >> 6;
    const int lane  = tid & 63;
    const int quad  = lane >> 4;
    const int lr    = lane & 15;
    const int b     = blockIdx.y;
    const int q0    = blockIdx.x * 64;
    const int kbase = blockIdx.z * SK;
    const short* qb = q + (size_t)b * S_ * H_;

    // Q A-fragments, resident whole kernel
    bf16x8 qa[2];
    {
        const short* qr = qb + (size_t)(q0 + wave * 16 + lr) * H_;
        qa[0] = *(const bf16x8*)(qr + quad * 8);
        qa[1] = *(const bf16x8*)(qr + 32 + quad * 8);
    }

    f32x4 o[4];
#pragma unroll
    for (int nb = 0; nb < 4; ++nb) o[nb] = (f32x4){0.f, 0.f, 0.f, 0.f};
    float l4[4] = {0.f, 0.f, 0.f, 0.f};

    const int sr = tid >> 3;          // 0..31
    const int sc = (tid & 7) * 8;     // 0..56
    const int t2 = tid & 7;
    uint4 pre0 = *(const uint4*)(qb + (size_t)(kbase + sr) * H_ + sc);
    uint4 pre1 = *(const uint4*)(qb + (size_t)(kbase + sr + 32) * H_ + sc);

    for (int kk = 0; kk < SK; kk += 64) {
        if (kk) __syncthreads();
        *(uint4*)&kt[sr][sc]      = pre0;
        *(uint4*)&kt[sr + 32][sc] = pre1;
        union { uint4 v; unsigned short s[8]; } u0, u1;
        u0.v = pre0; u1.v = pre1;
#pragma unroll
        for (int e = 0; e < 8; ++e) {
            const int ee = (e + t2) & 7;   // rotation: spread rows mod 8 across lanes
            vt[sc + ee][sr]      = (short)u0.s[ee];
            vt[sc + ee][sr + 32] = (short)u1.s[ee];
        }
        if (kk + 64 < SK) {
            pre0 = *(const uint4*)(qb + (size_t)(kbase + kk + 64 + sr) * H_ + sc);
            pre1 = *(const uint4*)(qb + (size_t)(kbase + kk + 96 + sr) * H_ + sc);
        }
        __syncthreads();

        // S = Q K^T
        f32x4 s[4];
#pragma unroll
        for (int nb = 0; nb < 4; ++nb) s[nb] = (f32x4){0.f, 0.f, 0.f, 0.f};
#pragma unroll
        for (int h = 0; h < 2; ++h) {
#pragma unroll
            for (int nb = 0; nb < 4; ++nb) {
                const bf16x8 bk = *(const bf16x8*)&kt[nb * 16 + lr][h * 32 + quad * 8];
                s[nb] = __builtin_amdgcn_mfma_f32_16x16x32_bf16(qa[h], bk, s[nb], 0, 0, 0);
            }
        }

        // P = exp(s*scale); per-lane row partial sums; P -> LDS bf16
#pragma unroll
        for (int nb = 0; nb < 4; ++nb) {
#pragma unroll
            for (int i = 0; i < 4; ++i) {
                const float p = __expf(s[nb][i] * SCALE_);
                l4[i] += p;
                pl[wave][quad * 4 + i][nb * 16 + lr] = f2bf(p);
            }
        }

        // O += P @ V
#pragma unroll
        for (int h = 0; h < 2; ++h) {
            const bf16x8 pa = *(const bf16x8*)&pl[wave][lr][h * 32 + quad * 8];
#pragma unroll
            for (int nb = 0; nb < 4; ++nb) {
                const bf16x8 bv = *(const bf16x8*)&vt[nb * 16 + lr][h * 32 + quad * 8];
                o[nb] = __builtin_amdgcn_mfma_f32_16x16x32_bf16(pa, bv, o[nb], 0, 0, 0);
            }
        }
    }

    // reduce row sums across the 16 lanes of each quad
#pragma unroll
    for (int i = 0; i < 4; ++i) {
        float v = l4[i];
        v += __shfl_xor(v, 1, 64);
        v += __shfl_xor(v, 2, 64);
        v += __shfl_xor(v, 4, 64);
        v += __shfl_xor(v, 8, 64);
        l4[i] = v;
    }

    // accumulate partials (4 split-K blocks per output tile)
    float* ob = out + ((size_t)b * S_ + q0 + wave * 16) * H_;
#pragma unroll
    for (int nb = 0; nb < 4; ++nb)
#pragma unroll
        for (int i = 0; i < 4; ++i)
            atomicAdd(&ob[(size_t)(quad * 4 + i) * H_ + nb * 16 + lr], o[nb][i]);
    if (lr == 0) {
#pragma unroll
        for (int i = 0; i < 4; ++i)
            atomicAdd(&lbuf[(size_t)b * S_ + q0 + wave * 16 + quad * 4 + i], l4[i]);
    }
}

// ---------------------------------------------------------------------------
// normalize: out[row, :] /= lbuf[row]
// ---------------------------------------------------------------------------
__global__ __launch_bounds__(256) void norm_kernel(
    float* __restrict__ out, const float* __restrict__ lbuf)
{
    const int t   = blockIdx.x * 256 + threadIdx.x;  // 65536 threads, 16 el each
    const int row = t >> 2;
    const int c0  = (t & 3) * 16;
    const float r = 1.0f / lbuf[row];
    f32x4* p = (f32x4*)(out + (size_t)row * H_ + c0);
#pragma unroll
    for (int j = 0; j < 4; ++j) {
        f32x4 v = p[j];
        v[0] *= r; v[1] *= r; v[2] *= r; v[3] *= r;
        p[j] = v;
    }
}

extern "C" void kernel_launch(void* const* d_in, const int* in_sizes, int n_in,
                              void* d_out, int out_size, void* d_ws, size_t ws_size,
                              hipStream_t stream) {
    const float* x  = (const float*)d_in[0];   // [4,4096,1024] f32
    const float* wq = (const float*)d_in[1];   // [64,1024] f32
    float* out = (float*)d_out;                // [4,4096,64] f32

    short* qbuf = (short*)d_ws;                               // 2 MiB bf16 q
    short* wqb  = (short*)((char*)d_ws + (2u << 20));         // 128 KiB bf16 wq
    float* lbuf = (float*)((char*)d_ws + (2u << 20) + (128u << 10)); // 64 KiB

    zinit_kernel<<<dim3(1024), dim3(256), 0, stream>>>(wq, wqb, out, lbuf);
    qproj_mfma<<<dim3((B_ * S_) / 16), dim3(256), 0, stream>>>(x, wqb, qbuf);
    flash_mfma<<<dim3(S_ / 64, B_, KSPLIT), dim3(256), 0, stream>>>(qbuf, out, lbuf);
    norm_kernel<<<dim3(256), dim3(256), 0, stream>>>(out, lbuf);
}

// Round 4
// 193.458 us; speedup vs baseline: 1.0323x; 1.0323x over previous
//
#include <hip/hip_runtime.h>
#include <hip/hip_bf16.h>

#define B_ 4
#define S_ 4096
#define D_ 1024
#define H_ 64
#define SCALE_ 0.125f

typedef __attribute__((ext_vector_type(8))) short bf16x8;
typedef __attribute__((ext_vector_type(4))) float f32x4;

// round-to-nearest-even f32 -> bf16 (finite inputs)
static __device__ __forceinline__ short f2bf(float f) {
    unsigned u = __builtin_bit_cast(unsigned, f);
    u += 0x7fffu + ((u >> 16) & 1u);
    return (short)(u >> 16);
}

// ---------------------------------------------------------------------------
// winit: wq f32 -> bf16 (65536 elements). Runs every launch (ws re-poisoned).
// ---------------------------------------------------------------------------
__global__ __launch_bounds__(256) void winit_kernel(
    const float* __restrict__ wq, short* __restrict__ wqb)
{
    const int i = blockIdx.x * 256 + threadIdx.x;   // 8192 threads x 8 el
    const float* s = wq + (size_t)i * 8;
    bf16x8 v;
#pragma unroll
    for (int e = 0; e < 8; ++e) v[e] = f2bf(s[e]);
    *(bf16x8*)(wqb + (size_t)i * 8) = v;
}

// ---------------------------------------------------------------------------
// qproj: q = x @ wq^T (bf16 MFMA), ALSO writes qT (transposed per batch).
// Block = 16 output rows; 4 waves split K=1024 into 4x256; LDS combine.
// ---------------------------------------------------------------------------
__global__ __launch_bounds__(256) void qproj_mfma(
    const float* __restrict__ x, const short* __restrict__ wqb,
    short* __restrict__ q, short* __restrict__ qT)
{
    __shared__ float cs[4][16][68];   // per-wave partial C
    __shared__ short qs[16][72];      // combined bf16 tile for qT transpose

    const int tid  = threadIdx.x;
    const int wave = tid >> 6;
    const int lane = tid & 63;
    const int quad = lane >> 4;
    const int lr   = lane & 15;
    const int row0 = blockIdx.x * 16;

    const float* xp = x   + (size_t)(row0 + lr) * D_ + wave * 256 + quad * 8;
    const short* wp = wqb + (size_t)lr * D_ + wave * 256 + quad * 8;

    f32x4 acc[4];
#pragma unroll
    for (int nb = 0; nb < 4; ++nb) acc[nb] = (f32x4){0.f, 0.f, 0.f, 0.f};

#pragma unroll
    for (int t = 0; t < 8; ++t) {
        const float* xpt = xp + t * 32;
        const f32x4 a0 = *(const f32x4*)xpt;
        const f32x4 a1 = *(const f32x4*)(xpt + 4);
        bf16x8 a;
#pragma unroll
        for (int e = 0; e < 4; ++e) {
            a[e]     = f2bf(a0[e]);
            a[e + 4] = f2bf(a1[e]);
        }
#pragma unroll
        for (int nb = 0; nb < 4; ++nb) {
            const bf16x8 b = *(const bf16x8*)(wp + (size_t)nb * 16 * D_ + t * 32);
            acc[nb] = __builtin_amdgcn_mfma_f32_16x16x32_bf16(a, b, acc[nb], 0, 0, 0);
        }
    }

    // stash per-wave partials (C-layout: row quad*4+i, col nb*16+lr)
#pragma unroll
    for (int nb = 0; nb < 4; ++nb)
#pragma unroll
        for (int i = 0; i < 4; ++i)
            cs[wave][quad * 4 + i][nb * 16 + lr] = acc[nb][i];
    __syncthreads();

    // combine 4 partials; thread owns (row r, cols c4..c4+3)
    const int r  = tid >> 4;
    const int c4 = (tid & 15) * 4;
    unsigned long long pv = 0;
    short s4[4];
#pragma unroll
    for (int j = 0; j < 4; ++j) {
        const float s = cs[0][r][c4 + j] + cs[1][r][c4 + j]
                      + cs[2][r][c4 + j] + cs[3][r][c4 + j];
        s4[j] = f2bf(s);
        pv |= (unsigned long long)(unsigned short)s4[j] << (16 * j);
    }
    *(unsigned long long*)(q + (size_t)(row0 + r) * H_ + c4) = pv;
    *(unsigned long long*)&qs[r][c4] = pv;   // row stride 144B -> 8B aligned
    __syncthreads();

    // qT[b][h][s]: thread -> h = tid>>2, 4 consecutive s at sj
    const int hh = tid >> 2;          // 0..63
    const int sj = (tid & 3) * 4;     // 0,4,8,12
    const int b  = row0 >> 12;        // 4096 rows per batch, 16 | 4096
    const int sl = row0 & (S_ - 1);
    unsigned long long w = 0;
#pragma unroll
    for (int e = 0; e < 4; ++e)
        w |= (unsigned long long)(unsigned short)qs[sj + e][hh] << (16 * e);
    *(unsigned long long*)(qT + ((size_t)b * H_ + hh) * S_ + sl + sj) = w;
}

// ---------------------------------------------------------------------------
// flash: k = v = q, bf16 MFMA, no online max (|s*scale| <~ 15, f32-safe).
// Block = 32 Q-rows shared by 4 waves; wave w owns K-slice [w*1024,(w+1)*1024).
// B-fragments (K rows from q, V^T rows from qT) loaded global->register
// directly (L2-resident, 16B/lane). LDS: per-wave P round-trip + final
// partial-O/l combine. NO barriers in the k-loop, no atomics.
// ---------------------------------------------------------------------------
__global__ __launch_bounds__(256) void flash_mfma(
    const short* __restrict__ q, const short* __restrict__ qT,
    float* __restrict__ out)
{
    __shared__ short pl[4][32][72];       // per-wave P [qrow][kcol], +8 pad
    __shared__ float opart[4][32][68];    // per-wave partial O
    __shared__ float lpart[4][32];        // per-wave partial row sums

    const int tid   = threadIdx.x;
    const int wave  = tid >> 6;
    const int lane  = tid & 63;
    const int quad  = lane >> 4;
    const int lr    = lane & 15;
    const int b     = blockIdx.y;
    const int q0    = blockIdx.x * 32;
    const int kbase = wave * (S_ / 4);
    const short* qb  = q  + (size_t)b * S_ * H_;
    const short* qTb = qT + (size_t)b * H_ * S_;

    // Q A-fragments, 2 sets of 16 rows, resident whole kernel
    bf16x8 qa[2][2];
#pragma unroll
    for (int set = 0; set < 2; ++set) {
        const short* qr = qb + (size_t)(q0 + set * 16 + lr) * H_;
        qa[set][0] = *(const bf16x8*)(qr + quad * 8);
        qa[set][1] = *(const bf16x8*)(qr + 32 + quad * 8);
    }

    f32x4 o[2][4];
#pragma unroll
    for (int set = 0; set < 2; ++set)
#pragma unroll
        for (int nb = 0; nb < 4; ++nb) o[set][nb] = (f32x4){0.f, 0.f, 0.f, 0.f};
    float l4[2][4] = {{0.f, 0.f, 0.f, 0.f}, {0.f, 0.f, 0.f, 0.f}};

    const short* bk_base = qb  + (size_t)kbase * H_ + (size_t)lr * H_ + quad * 8;
    const short* bv_base = qTb + (size_t)lr * S_ + kbase + quad * 8;

    for (int kk = 0; kk < S_ / 4; kk += 64) {
        // ---- S = Q K^T : B-frags straight from global (L2-hot) ----
        f32x4 s[2][4];
#pragma unroll
        for (int set = 0; set < 2; ++set)
#pragma unroll
            for (int nb = 0; nb < 4; ++nb) s[set][nb] = (f32x4){0.f, 0.f, 0.f, 0.f};
#pragma unroll
        for (int h = 0; h < 2; ++h) {
#pragma unroll
            for (int nb = 0; nb < 4; ++nb) {
                const bf16x8 bk = *(const bf16x8*)(bk_base + (size_t)(kk + nb * 16) * H_ + h * 32);
                s[0][nb] = __builtin_amdgcn_mfma_f32_16x16x32_bf16(qa[0][h], bk, s[0][nb], 0, 0, 0);
                s[1][nb] = __builtin_amdgcn_mfma_f32_16x16x32_bf16(qa[1][h], bk, s[1][nb], 0, 0, 0);
            }
        }

        // ---- P = exp(s*scale); row partials; P -> LDS bf16 ----
#pragma unroll
        for (int set = 0; set < 2; ++set)
#pragma unroll
            for (int nb = 0; nb < 4; ++nb)
#pragma unroll
                for (int i = 0; i < 4; ++i) {
                    const float p = __expf(s[set][nb][i] * SCALE_);
                    l4[set][i] += p;
                    pl[wave][set * 16 + quad * 4 + i][nb * 16 + lr] = f2bf(p);
                }

        // ---- O += P @ V : A from pl, B (V^T rows) straight from qT ----
#pragma unroll
        for (int h = 0; h < 2; ++h) {
            const bf16x8 pa0 = *(const bf16x8*)&pl[wave][lr][h * 32 + quad * 8];
            const bf16x8 pa1 = *(const bf16x8*)&pl[wave][16 + lr][h * 32 + quad * 8];
#pragma unroll
            for (int nb = 0; nb < 4; ++nb) {
                const bf16x8 bv = *(const bf16x8*)(bv_base + (size_t)(nb * 16) * S_ + kk + h * 32);
                o[0][nb] = __builtin_amdgcn_mfma_f32_16x16x32_bf16(pa0, bv, o[0][nb], 0, 0, 0);
                o[1][nb] = __builtin_amdgcn_mfma_f32_16x16x32_bf16(pa1, bv, o[1][nb], 0, 0, 0);
            }
        }
    }

    // per-wave row-sum reduce across the 16 lr lanes of each quad
#pragma unroll
    for (int set = 0; set < 2; ++set)
#pragma unroll
        for (int i = 0; i < 4; ++i) {
            float v = l4[set][i];
            v += __shfl_xor(v, 1, 64);
            v += __shfl_xor(v, 2, 64);
            v += __shfl_xor(v, 4, 64);
            v += __shfl_xor(v, 8, 64);
            if (lr == 0) lpart[wave][set * 16 + quad * 4 + i] = v;
        }

    // stash partial O
#pragma unroll
    for (int set = 0; set < 2; ++set)
#pragma unroll
        for (int nb = 0; nb < 4; ++nb)
#pragma unroll
            for (int i = 0; i < 4; ++i)
                opart[wave][set * 16 + quad * 4 + i][nb * 16 + lr] = o[set][nb][i];
    __syncthreads();

    // combine 4 K-slices; thread -> row r, 8 cols at c0
    const int r  = tid >> 3;
    const int c0 = (tid & 7) * 8;
    const float linv = 1.0f / (lpart[0][r] + lpart[1][r] + lpart[2][r] + lpart[3][r]);
    float res[8];
#pragma unroll
    for (int j = 0; j < 8; ++j) {
        const int c = c0 + j;
        res[j] = (opart[0][r][c] + opart[1][r][c] + opart[2][r][c] + opart[3][r][c]) * linv;
    }
    float* op = out + ((size_t)b * S_ + q0 + r) * H_ + c0;
    *(f32x4*)op       = (f32x4){res[0], res[1], res[2], res[3]};
    *(f32x4*)(op + 4) = (f32x4){res[4], res[5], res[6], res[7]};
}

extern "C" void kernel_launch(void* const* d_in, const int* in_sizes, int n_in,
                              void* d_out, int out_size, void* d_ws, size_t ws_size,
                              hipStream_t stream) {
    const float* x  = (const float*)d_in[0];   // [4,4096,1024] f32
    const float* wq = (const float*)d_in[1];   // [64,1024] f32
    float* out = (float*)d_out;                // [4,4096,64] f32

    short* qbuf = (short*)d_ws;                        // 2 MiB bf16 q [B*S][64]
    short* qT   = (short*)((char*)d_ws + (2u << 20));  // 2 MiB bf16 qT [B][64][S]
    short* wqb  = (short*)((char*)d_ws + (4u << 20));  // 128 KiB bf16 wq

    winit_kernel<<<dim3(32), dim3(256), 0, stream>>>(wq, wqb);
    qproj_mfma<<<dim3((B_ * S_) / 16), dim3(256), 0, stream>>>(x, wqb, qbuf, qT);
    flash_mfma<<<dim3(S_ / 32, B_), dim3(256), 0, stream>>>(qbuf, qT, out);
}

// Round 5
// 183.676 us; speedup vs baseline: 1.0873x; 1.0533x over previous
//
#include <hip/hip_runtime.h>
#include <hip/hip_bf16.h>

#define B_ 4
#define S_ 4096
#define D_ 1024
#define H_ 64
#define SCALE_ 0.125f
#define WP_ 1056   // padded wq row stride in shorts (2112 B = 8.25 granules -> 16 rows spread channels)
#define SP_ 4224   // padded qT row stride in shorts (8448 B = 33 granules -> 16 rows spread channels)

typedef __attribute__((ext_vector_type(8))) short bf16x8;
typedef __attribute__((ext_vector_type(4))) float f32x4;

// round-to-nearest-even f32 -> bf16 (finite inputs)
static __device__ __forceinline__ short f2bf(float f) {
    unsigned u = __builtin_bit_cast(unsigned, f);
    u += 0x7fffu + ((u >> 16) & 1u);
    return (short)(u >> 16);
}

// ---------------------------------------------------------------------------
// winit: wq f32 -> bf16 into padded [64][WP_] layout.
// ---------------------------------------------------------------------------
__global__ __launch_bounds__(256) void winit_kernel(
    const float* __restrict__ wq, short* __restrict__ wqb)
{
    const int i   = blockIdx.x * 256 + threadIdx.x;   // 8192 threads x 8 el
    const int row = i >> 7;             // 1024/8 = 128 chunks per row
    const int col = (i & 127) * 8;
    const float* s = wq + (size_t)row * D_ + col;
    bf16x8 v;
#pragma unroll
    for (int e = 0; e < 8; ++e) v[e] = f2bf(s[e]);
    *(bf16x8*)(wqb + (size_t)row * WP_ + col) = v;
}

// ---------------------------------------------------------------------------
// qproj: q = x @ wq^T (bf16 MFMA). Block = 16 output rows, 4 waves = 4
// K-quarters (256 d each). Each wave stages its 16x256 x-chunk f32->bf16
// into wave-private LDS with FULLY-COALESCED loads (16 consecutive lanes on
// one row -> 1KB contiguous segments; no pow2-stride gathers). wq B-frags
// direct from padded wqb (L2-hot, channel-spread). In-block LDS combine,
// writes q and channel-padded qT. Grid 1024 blocks = 4/CU.
// ---------------------------------------------------------------------------
__global__ __launch_bounds__(256) void qproj_mfma(
    const float* __restrict__ x, const short* __restrict__ wqb,
    short* __restrict__ q, short* __restrict__ qT)
{
    __shared__ short xs[4][16][264];  // per-wave bf16 A chunk (+8 pad)
    __shared__ float cs[4][16][68];   // per-wave partial C
    __shared__ short qs[16][68];      // combined bf16 tile for qT transpose

    const int tid  = threadIdx.x;
    const int wave = tid >> 6;        // = K-quarter
    const int lane = tid & 63;
    const int quad = lane >> 4;
    const int lr   = lane & 15;
    const int row0 = blockIdx.x * 16;

    // ---- stage 16 rows x 256 cols f32 -> bf16, coalesced ----
    // round r: thread (srow, scol): lanes 0..15 cover one row contiguously.
    {
        const int srow = lane >> 4;          // 0..3
        const int scol = (lane & 15) * 16;   // f32 col within chunk
        const float* xp = x + (size_t)(row0 + srow) * D_ + wave * 256 + scol;
#pragma unroll
        for (int r = 0; r < 4; ++r) {
            const float* xr = xp + (size_t)(r * 4) * D_;
            const f32x4 v0 = *(const f32x4*)(xr);
            const f32x4 v1 = *(const f32x4*)(xr + 4);
            const f32x4 v2 = *(const f32x4*)(xr + 8);
            const f32x4 v3 = *(const f32x4*)(xr + 12);
            bf16x8 b0, b1;
#pragma unroll
            for (int e = 0; e < 4; ++e) {
                b0[e] = f2bf(v0[e]); b0[e + 4] = f2bf(v1[e]);
                b1[e] = f2bf(v2[e]); b1[e + 4] = f2bf(v3[e]);
            }
            *(bf16x8*)&xs[wave][r * 4 + srow][scol]     = b0;
            *(bf16x8*)&xs[wave][r * 4 + srow][scol + 8] = b1;
        }
    }
    __syncthreads();

    f32x4 acc[4];
#pragma unroll
    for (int nb = 0; nb < 4; ++nb) acc[nb] = (f32x4){0.f, 0.f, 0.f, 0.f};

    const short* wp = wqb + (size_t)lr * WP_ + wave * 256 + quad * 8;
#pragma unroll
    for (int t = 0; t < 8; ++t) {
        const bf16x8 a = *(const bf16x8*)&xs[wave][lr][t * 32 + quad * 8];
#pragma unroll
        for (int nb = 0; nb < 4; ++nb) {
            const bf16x8 bb = *(const bf16x8*)(wp + (size_t)(nb * 16) * WP_ + t * 32);
            acc[nb] = __builtin_amdgcn_mfma_f32_16x16x32_bf16(a, bb, acc[nb], 0, 0, 0);
        }
    }

    // per-wave partials (C-layout: row quad*4+i, col nb*16+lr)
#pragma unroll
    for (int nb = 0; nb < 4; ++nb)
#pragma unroll
        for (int i = 0; i < 4; ++i)
            cs[wave][quad * 4 + i][nb * 16 + lr] = acc[nb][i];
    __syncthreads();

    // combine 4 K-quarters; thread -> (row r, cols c4..c4+3)
    const int r  = tid >> 4;
    const int c4 = (tid & 15) * 4;
    unsigned long long pv = 0;
#pragma unroll
    for (int j = 0; j < 4; ++j) {
        const float s = cs[0][r][c4 + j] + cs[1][r][c4 + j]
                      + cs[2][r][c4 + j] + cs[3][r][c4 + j];
        pv |= (unsigned long long)(unsigned short)f2bf(s) << (16 * j);
    }
    *(unsigned long long*)(q + (size_t)(row0 + r) * H_ + c4) = pv;
    *(unsigned long long*)&qs[r][c4] = pv;
    __syncthreads();

    // qT[b][h][s] (padded stride SP_): thread -> h = tid>>2, 4 s-values
    const int hh = tid >> 2;          // 0..63
    const int sj = (tid & 3) * 4;     // 0,4,8,12
    const int b  = row0 >> 12;
    const int sl = row0 & (S_ - 1);
    unsigned long long w = 0;
#pragma unroll
    for (int e = 0; e < 4; ++e)
        w |= (unsigned long long)(unsigned short)qs[sj + e][hh] << (16 * e);
    *(unsigned long long*)(qT + ((size_t)b * H_ + hh) * SP_ + sl + sj) = w;
}

// ---------------------------------------------------------------------------
// flash: k = v = q, bf16 MFMA, no online max (|s*scale| <~ 15, f32-safe).
// Block = 32 Q-rows shared by 4 waves; wave w owns K-slice [w*1024,(w+1)*1024).
// B-fragments: K rows from q (128B stride, contiguous -> fine), V^T rows from
// CHANNEL-PADDED qT (stride SP_, no pow2 serialization). LDS: per-wave P
// round-trip + final partial-O/l combine. No k-loop barriers, no atomics.
// ---------------------------------------------------------------------------
__global__ __launch_bounds__(256) void flash_mfma(
    const short* __restrict__ q, const short* __restrict__ qT,
    float* __restrict__ out)
{
    __shared__ short pl[4][32][72];       // per-wave P [qrow][kcol]
    __shared__ float opart[4][32][68];    // per-wave partial O
    __shared__ float lpart[4][32];        // per-wave partial row sums

    const int tid   = threadIdx.x;
    const int wave  = tid >> 6;
    const int lane  = tid & 63;
    const int quad  = lane >> 4;
    const int lr    = lane & 15;
    const int b     = blockIdx.y;
    const int q0    = blockIdx.x * 32;
    const int kbase = wave * (S_ / 4);
    const short* qb  = q  + (size_t)b * S_ * H_;
    const short* qTb = qT + (size_t)b * H_ * SP_;

    // Q A-fragments, 2 sets of 16 rows, resident whole kernel
    bf16x8 qa[2][2];
#pragma unroll
    for (int set = 0; set < 2; ++set) {
        const short* qr = qb + (size_t)(q0 + set * 16 + lr) * H_;
        qa[set][0] = *(const bf16x8*)(qr + quad * 8);
        qa[set][1] = *(const bf16x8*)(qr + 32 + quad * 8);
    }

    f32x4 o[2][4];
#pragma unroll
    for (int set = 0; set < 2; ++set)
#pragma unroll
        for (int nb = 0; nb < 4; ++nb) o[set][nb] = (f32x4){0.f, 0.f, 0.f, 0.f};
    float l4[2][4] = {{0.f, 0.f, 0.f, 0.f}, {0.f, 0.f, 0.f, 0.f}};

    const short* bk_base = qb  + (size_t)(kbase + lr) * H_ + quad * 8;
    const short* bv_base = qTb + (size_t)lr * SP_ + kbase + quad * 8;

    for (int kk = 0; kk < S_ / 4; kk += 64) {
        // ---- S = Q K^T : B-frags straight from global (L2-hot) ----
        f32x4 s[2][4];
#pragma unroll
        for (int set = 0; set < 2; ++set)
#pragma unroll
            for (int nb = 0; nb < 4; ++nb) s[set][nb] = (f32x4){0.f, 0.f, 0.f, 0.f};
#pragma unroll
        for (int h = 0; h < 2; ++h) {
#pragma unroll
            for (int nb = 0; nb < 4; ++nb) {
                const bf16x8 bk = *(const bf16x8*)(bk_base + (size_t)(kk + nb * 16) * H_ + h * 32);
                s[0][nb] = __builtin_amdgcn_mfma_f32_16x16x32_bf16(qa[0][h], bk, s[0][nb], 0, 0, 0);
                s[1][nb] = __builtin_amdgcn_mfma_f32_16x16x32_bf16(qa[1][h], bk, s[1][nb], 0, 0, 0);
            }
        }

        // ---- P = exp(s*scale); row partials; P -> LDS bf16 ----
#pragma unroll
        for (int set = 0; set < 2; ++set)
#pragma unroll
            for (int nb = 0; nb < 4; ++nb)
#pragma unroll
                for (int i = 0; i < 4; ++i) {
                    const float p = __expf(s[set][nb][i] * SCALE_);
                    l4[set][i] += p;
                    pl[wave][set * 16 + quad * 4 + i][nb * 16 + lr] = f2bf(p);
                }

        // ---- O += P @ V : A from pl, B (V^T rows) from padded qT ----
#pragma unroll
        for (int h = 0; h < 2; ++h) {
            const bf16x8 pa0 = *(const bf16x8*)&pl[wave][lr][h * 32 + quad * 8];
            const bf16x8 pa1 = *(const bf16x8*)&pl[wave][16 + lr][h * 32 + quad * 8];
#pragma unroll
            for (int nb = 0; nb < 4; ++nb) {
                const bf16x8 bv = *(const bf16x8*)(bv_base + (size_t)(nb * 16) * SP_ + kk + h * 32);
                o[0][nb] = __builtin_amdgcn_mfma_f32_16x16x32_bf16(pa0, bv, o[0][nb], 0, 0, 0);
                o[1][nb] = __builtin_amdgcn_mfma_f32_16x16x32_bf16(pa1, bv, o[1][nb], 0, 0, 0);
            }
        }
    }

    // per-wave row-sum reduce across the 16 lr lanes of each quad
#pragma unroll
    for (int set = 0; set < 2; ++set)
#pragma unroll
        for (int i = 0; i < 4; ++i) {
            float v = l4[set][i];
            v += __shfl_xor(v, 1, 64);
            v += __shfl_xor(v, 2, 64);
            v += __shfl_xor(v, 4, 64);
            v += __shfl_xor(v, 8, 64);
            if (lr == 0) lpart[wave][set * 16 + quad * 4 + i] = v;
        }

    // stash partial O
#pragma unroll
    for (int set = 0; set < 2; ++set)
#pragma unroll
        for (int nb = 0; nb < 4; ++nb)
#pragma unroll
            for (int i = 0; i < 4; ++i)
                opart[wave][set * 16 + quad * 4 + i][nb * 16 + lr] = o[set][nb][i];
    __syncthreads();

    // combine 4 K-slices; thread -> row r, 8 cols at c0
    const int r  = tid >> 3;
    const int c0 = (tid & 7) * 8;
    const float linv = 1.0f / (lpart[0][r] + lpart[1][r] + lpart[2][r] + lpart[3][r]);
    float res[8];
#pragma unroll
    for (int j = 0; j < 8; ++j) {
        const int c = c0 + j;
        res[j] = (opart[0][r][c] + opart[1][r][c] + opart[2][r][c] + opart[3][r][c]) * linv;
    }
    float* op = out + ((size_t)b * S_ + q0 + r) * H_ + c0;
    *(f32x4*)op       = (f32x4){res[0], res[1], res[2], res[3]};
    *(f32x4*)(op + 4) = (f32x4){res[4], res[5], res[6], res[7]};
}

extern "C" void kernel_launch(void* const* d_in, const int* in_sizes, int n_in,
                              void* d_out, int out_size, void* d_ws, size_t ws_size,
                              hipStream_t stream) {
    const float* x  = (const float*)d_in[0];   // [4,4096,1024] f32
    const float* wq = (const float*)d_in[1];   // [64,1024] f32
    float* out = (float*)d_out;                // [4,4096,64] f32

    // ws layout: q 2 MiB | qT (padded) ~2.06 MiB | wqb (padded) ~132 KiB
    short* qbuf = (short*)d_ws;
    short* qT   = (short*)((char*)d_ws + (2u << 20));
    short* wqb  = (short*)((char*)d_ws + (2u << 20) + (size_t)B_ * H_ * SP_ * 2);

    winit_kernel<<<dim3(32), dim3(256), 0, stream>>>(wq, wqb);
    qproj_mfma<<<dim3((B_ * S_) / 16), dim3(256), 0, stream>>>(x, wqb, qbuf, qT);
    flash_mfma<<<dim3(S_ / 32, B_), dim3(256), 0, stream>>>(qbuf, qT, out);
}